// Round 1
// baseline (725.533 us; speedup 1.0000x reference)
//
#include <hip/hip_runtime.h>
#include <hip/hip_bf16.h>

// ConvLayer: 3x3 s1 p1 conv, x=(256,512,512) f32, W=(3,3,256,256) HWIO, out=(256,512,512) f32.
// Strategy: bf16 implicit GEMM on MFMA (m97 structure).
//   pass1: xt[h][w][ci] = bf16(x[ci][h][w])        (128 MiB in ws)
//   pass2: Wt[kh][kw][co][ci] = bf16(W[kh][kw][ci][co])  (1.1 MiB in ws) + 128B zero line
//   pass3: out[co][h][w] = sum_{kh,kw,ci} Wt.Xt + b  via 128x128 tile, 16x16x32 bf16 MFMA,
//          global_load_lds width16, 130-row haloed B tile shared across the 3 kw taps.

typedef __attribute__((ext_vector_type(8))) short bf16x8;
typedef __attribute__((ext_vector_type(4))) float floatx4;

#define HWSZ 262144   // 512*512
#define CIN  256
#define HH   512
#define WWD  512

__device__ __forceinline__ void async_copy16(const void* g, void* l) {
  __builtin_amdgcn_global_load_lds(
      (const __attribute__((address_space(1))) void*)g,
      (__attribute__((address_space(3))) void*)l, 16, 0, 0);
}

// ---------------- pass 1: x f32 [ci][h][w] -> xt bf16 [h][w][ci] ----------------
// grid 8192 blocks x 256 thr. block: 32 ci x 256 w for one h. thread: 8 ci x 4 w.
__global__ __launch_bounds__(256) void convert_x(
    const float* __restrict__ x, __hip_bfloat16* __restrict__ xt)
{
  const int b   = blockIdx.x;
  const int wt  = b & 1;            // w half
  const int cit = (b >> 1) & 7;     // ci tile of 32
  const int h   = b >> 4;           // 0..511
  const int t   = threadIdx.x;
  const int cq  = t & 3;            // 8-ci subgroup
  const int wq  = t >> 2;           // 64 groups of 4 w
  const int ci  = (cit << 5) + (cq << 3);
  const int w   = (wt << 8) + (wq << 2);

  const float* xp = x + (size_t)ci * HWSZ + (size_t)h * WWD + w;
  float4 v[8];
#pragma unroll
  for (int s = 0; s < 8; ++s)
    v[s] = *(const float4*)(xp + (size_t)s * HWSZ);

#pragma unroll
  for (int r = 0; r < 4; ++r) {
    union { __hip_bfloat16 bh[8]; uint4 u; } pk;
#pragma unroll
    for (int s = 0; s < 8; ++s) {
      float f = (r == 0) ? v[s].x : (r == 1) ? v[s].y : (r == 2) ? v[s].z : v[s].w;
      pk.bh[s] = __float2bfloat16(f);
    }
    *(uint4*)&xt[(((size_t)h * WWD + (w + r)) << 8) + ci] = pk.u;
  }
}

// ---------------- pass 2: W f32 [kh][kw][ci][co] -> Wt bf16 [kh][kw][co][ci]; zero line ----
__global__ __launch_bounds__(256) void convert_w(
    const float* __restrict__ Wf, __hip_bfloat16* __restrict__ wt,
    __hip_bfloat16* __restrict__ zb)
{
  const int idx = blockIdx.x * 256 + threadIdx.x;   // < 589824
  const int ci = idx & 255;
  const int co = (idx >> 8) & 255;
  const int kk = idx >> 16;                          // 0..8
  wt[((size_t)(kk * 256 + co) << 8) + ci] =
      __float2bfloat16(Wf[((size_t)(kk * 256 + ci) << 8) + co]);
  if (idx < 64) zb[idx] = __float2bfloat16(0.0f);
}

// ---------------- pass 3: MFMA implicit-GEMM conv ----------------
// grid 4096 = 512 h * 2 co-tiles * 4 w-tiles; block 256 thr = 4 waves (2x2 of 64x64).
__global__ __launch_bounds__(256, 3) void conv_mfma(
    const __hip_bfloat16* __restrict__ xt,   // [512][512][256]
    const __hip_bfloat16* __restrict__ wt,   // [9][256][256] (co-major rows, ci contiguous)
    const float* __restrict__ bias,
    float* __restrict__ out,                 // [256][512][512]
    const __hip_bfloat16* __restrict__ zb)
{
  __shared__ __align__(16) __hip_bfloat16 As[3 * 128 * 32];  // [kw][m][k] 24576 B
  __shared__ __align__(16) __hip_bfloat16 Bs[130 * 32];      // [r][k]     8320 B

  const int b    = blockIdx.x;
  const int wti  = b & 3;
  const int cot  = (b >> 2) & 1;
  const int h    = b >> 3;
  const int w0   = wti << 7;
  const int co0  = cot << 7;
  const int t    = threadIdx.x;
  const int lane = t & 63;
  const int wave = t >> 6;
  const int wm   = wave & 1;    // co half within tile
  const int wn   = wave >> 1;   // w half within tile
  const int mcol = lane & 15;
  const int krow = lane >> 4;

  floatx4 acc[4][4];
#pragma unroll
  for (int mi = 0; mi < 4; ++mi)
#pragma unroll
    for (int ni = 0; ni < 4; ++ni) {
      floatx4 z = {0.f, 0.f, 0.f, 0.f};
      acc[mi][ni] = z;
    }

  for (int kh = 0; kh < 3; ++kh) {
    const int hp = h + kh - 1;
    const bool hok = (unsigned)hp < (unsigned)HH;
    const __hip_bfloat16* xrow = xt + (size_t)hp * (WWD * CIN);

    for (int ci0 = 0; ci0 < CIN; ci0 += 32) {
      __syncthreads();
      // stage A: 3 kw x 128 co-rows x 64 B  = 1536 16B chunks
#pragma unroll
      for (int rnd = 0; rnd < 6; ++rnd) {
        int c  = rnd * 256 + t;
        int kw = c >> 9;
        int m  = (c >> 2) & 127;
        int j  = c & 3;
        const __hip_bfloat16* g =
            wt + (((size_t)((kh * 3 + kw) * 256 + co0 + m)) << 8) + ci0 + (j << 3);
        async_copy16(g, &As[c << 3]);
      }
      // stage B: 130 haloed w-rows x 64 B = 520 chunks
#pragma unroll
      for (int rnd = 0; rnd < 2; ++rnd) {
        int c = rnd * 256 + t;
        int r = c >> 2;
        int j = c & 3;
        int wp = w0 - 1 + r;
        const __hip_bfloat16* g = (hok && (unsigned)wp < (unsigned)WWD)
            ? xrow + ((size_t)wp << 8) + ci0 + (j << 3)
            : zb + (j << 3);
        async_copy16(g, &Bs[c << 3]);
      }
      if (t < 8) {
        int c = 512 + t;
        int r = c >> 2;
        int j = c & 3;
        int wp = w0 - 1 + r;
        const __hip_bfloat16* g = (hok && (unsigned)wp < (unsigned)WWD)
            ? xrow + ((size_t)wp << 8) + ci0 + (j << 3)
            : zb + (j << 3);
        async_copy16(g, &Bs[c << 3]);
      }
      __syncthreads();

#pragma unroll
      for (int kw = 0; kw < 3; ++kw) {
        bf16x8 af[4], bfr[4];
#pragma unroll
        for (int mi = 0; mi < 4; ++mi)
          af[mi] = *(const bf16x8*)&As[(kw << 12) + ((wm * 64 + mi * 16 + mcol) << 5) + (krow << 3)];
#pragma unroll
        for (int ni = 0; ni < 4; ++ni)
          bfr[ni] = *(const bf16x8*)&Bs[((wn * 64 + ni * 16 + mcol + kw) << 5) + (krow << 3)];
#pragma unroll
        for (int mi = 0; mi < 4; ++mi)
#pragma unroll
          for (int ni = 0; ni < 4; ++ni)
            acc[mi][ni] = __builtin_amdgcn_mfma_f32_16x16x32_bf16(
                af[mi], bfr[ni], acc[mi][ni], 0, 0, 0);
      }
    }
  }

  // epilogue: D col = lane&15, row = (lane>>4)*4 + reg (m91-verified)
  const size_t outrow = (size_t)h * WWD;
#pragma unroll
  for (int mi = 0; mi < 4; ++mi) {
#pragma unroll
    for (int r = 0; r < 4; ++r) {
      int co = co0 + wm * 64 + mi * 16 + krow * 4 + r;
      float bv = bias[co];
      float* op = out + (size_t)co * HWSZ + outrow + w0 + wn * 64 + mcol;
#pragma unroll
      for (int ni = 0; ni < 4; ++ni)
        op[ni * 16] = acc[mi][ni][r] + bv;
    }
  }
}

// ---------------- fallback: naive fp32 direct conv (only if ws too small) ----------------
__global__ __launch_bounds__(256) void conv_naive(
    const float* __restrict__ x, const float* __restrict__ Wf,
    const float* __restrict__ bias, float* __restrict__ out)
{
  size_t idx = (size_t)blockIdx.x * 256 + threadIdx.x;
  int w  = (int)(idx & 511);
  int h  = (int)((idx >> 9) & 511);
  int co = (int)(idx >> 18);
  float acc = bias[co];
  for (int kh = 0; kh < 3; ++kh) {
    int hp = h + kh - 1;
    if ((unsigned)hp >= 512u) continue;
    for (int kw = 0; kw < 3; ++kw) {
      int wp = w + kw - 1;
      if ((unsigned)wp >= 512u) continue;
      const float* wcol = Wf + ((size_t)(kh * 3 + kw) << 16) + co;
      const float* xpix = x + (size_t)hp * 512 + wp;
      for (int ci = 0; ci < 256; ++ci)
        acc += xpix[(size_t)ci * HWSZ] * wcol[(size_t)ci << 8];
    }
  }
  out[idx] = acc;
}

extern "C" void kernel_launch(void* const* d_in, const int* in_sizes, int n_in,
                              void* d_out, int out_size, void* d_ws, size_t ws_size,
                              hipStream_t stream) {
  const float* x    = (const float*)d_in[0];
  const float* Wf   = (const float*)d_in[1];
  const float* bias = (const float*)d_in[2];
  float* out = (float*)d_out;

  const size_t xt_bytes = (size_t)HH * WWD * CIN * 2;        // 134217728
  const size_t wt_bytes = (size_t)9 * 256 * 256 * 2;         // 1179648
  const size_t need = xt_bytes + wt_bytes + 256;

  if (ws_size >= need) {
    __hip_bfloat16* xt = (__hip_bfloat16*)d_ws;
    __hip_bfloat16* wt = (__hip_bfloat16*)((char*)d_ws + xt_bytes);
    __hip_bfloat16* zb = (__hip_bfloat16*)((char*)d_ws + xt_bytes + wt_bytes);
    convert_x<<<8192, 256, 0, stream>>>(x, xt);
    convert_w<<<2304, 256, 0, stream>>>(Wf, wt, zb);
    conv_mfma<<<4096, 256, 0, stream>>>(xt, wt, bias, out, zb);
  } else {
    conv_naive<<<262144, 256, 0, stream>>>(x, Wf, bias, out);
  }
}

// Round 3
// 718.300 us; speedup vs baseline: 1.0101x; 1.0101x over previous
//
#include <hip/hip_runtime.h>
#include <hip/hip_bf16.h>

// ConvLayer: 3x3 s1 p1 conv, x=(256,512,512) f32, W=(3,3,256,256) HWIO, out=(256,512,512) f32.
// Strategy: bf16 implicit GEMM on MFMA (m97 structure).
//   pass1: xt[h][w][ci] = bf16(x[ci][h][w])   via 32KB LDS transpose tile, XOR-swizzled
//   pass2: Wt[kh][kw][co][ci] = bf16(W[kh][kw][ci][co])  + 128B zero line
//   pass3: out[co][h][w] via 128x128 tile, 16x16x32 bf16 MFMA, global_load_lds width16,
//          130-row haloed B tile shared across the 3 kw taps.

typedef __attribute__((ext_vector_type(8))) short bf16x8;
typedef __attribute__((ext_vector_type(4))) float floatx4;

#define HWSZ 262144   // 512*512
#define CIN  256
#define HH   512
#define WWD  512

__device__ __forceinline__ void async_copy16(const void* g, void* l) {
  __builtin_amdgcn_global_load_lds(
      (const __attribute__((address_space(1))) void*)g,
      (__attribute__((address_space(3))) void*)l, 16, 0, 0);
}

// ---------------- pass 1: x f32 [ci][h][w] -> xt bf16 [h][w][ci] ----------------
// grid 4096 = 512 h x 8 w-tiles; block 256 thr. Tile: 64 pixels x 256 ci.
// Phase 1: coalesced read along w, scalar-scatter into swizzled pixel-major LDS.
// Phase 2: coalesced 16B reads from LDS, full 512B pixel rows to global.
// Swizzle: element (p, ci) at byte  p*512 + (((ci>>3) ^ (p>>2)) << 4) + (ci&7)*2.
//  - bijective per pixel row (pure chunk permutation)
//  - phase-2 reads: lane m reads chunk (m ^ (p>>2)) -> banks uniform, at 1024B/instr floor
//  - phase-1 writes: ~4-way conflict on 2B writes (cheap)
__global__ __launch_bounds__(256) void convert_x(
    const float* __restrict__ x, __hip_bfloat16* __restrict__ xt)
{
  __shared__ __align__(16) unsigned char lds[64 * 512];  // 32 KB
  const int b  = blockIdx.x;
  const int wt = b & 7;
  const int h  = b >> 3;
  const int w0 = wt << 6;
  const int t  = threadIdx.x;

  // phase 1: 16 iterations x (16 ci-rows x 64 w) per block
  const int lane16 = t & 15;   // w quad
  const int cidx   = t >> 4;   // ci sub-row 0..15
  const float* xrow = x + (size_t)h * WWD + w0 + lane16 * 4;
#pragma unroll 4
  for (int cit = 0; cit < 16; ++cit) {
    int ci = cit * 16 + cidx;
    float4 v = *(const float4*)(xrow + (size_t)ci * HWSZ);
    float f[4] = {v.x, v.y, v.z, v.w};
#pragma unroll
    for (int j = 0; j < 4; ++j) {
      int p = lane16 * 4 + j;
      int chunk = (ci >> 3) ^ (p >> 2);
      *(__hip_bfloat16*)&lds[p * 512 + chunk * 16 + (ci & 7) * 2] =
          __float2bfloat16(f[j]);
    }
  }
  __syncthreads();

  // phase 2: 8 iterations x (8 pixels x 32 chunks)
  const int m  = t & 31;
  const int pq = t >> 5;
#pragma unroll
  for (int it = 0; it < 8; ++it) {
    int p = it * 8 + pq;
    uint4 v = *(const uint4*)&lds[p * 512 + ((m ^ (p >> 2)) << 4)];
    *(uint4*)&xt[(((size_t)h * WWD + w0 + p) << 8) + m * 8] = v;
  }
}

// ---------------- pass 2: W f32 [kh][kw][ci][co] -> Wt bf16 [kh][kw][co][ci]; zero line ----
__global__ __launch_bounds__(256) void convert_w(
    const float* __restrict__ Wf, __hip_bfloat16* __restrict__ wt,
    __hip_bfloat16* __restrict__ zb)
{
  const int idx = blockIdx.x * 256 + threadIdx.x;   // < 589824
  const int ci = idx & 255;
  const int co = (idx >> 8) & 255;
  const int kk = idx >> 16;                          // 0..8
  wt[((size_t)(kk * 256 + co) << 8) + ci] =
      __float2bfloat16(Wf[((size_t)(kk * 256 + ci) << 8) + co]);
  if (idx < 64) zb[idx] = __float2bfloat16(0.0f);
}

// ---------------- pass 3: MFMA implicit-GEMM conv ----------------
// grid 4096 = 512 h * 2 co-tiles * 4 w-tiles; block 256 thr = 4 waves (2x2 of 64x64).
__global__ __launch_bounds__(256, 3) void conv_mfma(
    const __hip_bfloat16* __restrict__ xt,   // [512][512][256]
    const __hip_bfloat16* __restrict__ wt,   // [9][256][256] (co-major rows, ci contiguous)
    const float* __restrict__ bias,
    float* __restrict__ out,                 // [256][512][512]
    const __hip_bfloat16* __restrict__ zb)
{
  __shared__ __align__(16) __hip_bfloat16 As[3 * 128 * 32];  // [kw][m][k] 24576 B
  __shared__ __align__(16) __hip_bfloat16 Bs[130 * 32];      // [r][k]     8320 B

  const int b    = blockIdx.x;
  const int wti  = b & 3;
  const int cot  = (b >> 2) & 1;
  const int h    = b >> 3;
  const int w0   = wti << 7;
  const int co0  = cot << 7;
  const int t    = threadIdx.x;
  const int lane = t & 63;
  const int wave = t >> 6;
  const int wm   = wave & 1;    // co half within tile
  const int wn   = wave >> 1;   // w half within tile
  const int mcol = lane & 15;
  const int krow = lane >> 4;

  floatx4 acc[4][4];
#pragma unroll
  for (int mi = 0; mi < 4; ++mi)
#pragma unroll
    for (int ni = 0; ni < 4; ++ni) {
      floatx4 z = {0.f, 0.f, 0.f, 0.f};
      acc[mi][ni] = z;
    }

  for (int kh = 0; kh < 3; ++kh) {
    const int hp = h + kh - 1;
    const bool hok = (unsigned)hp < (unsigned)HH;
    const __hip_bfloat16* xrow = xt + (size_t)hp * (WWD * CIN);

    for (int ci0 = 0; ci0 < CIN; ci0 += 32) {
      __syncthreads();
      // stage A: 3 kw x 128 co-rows x 64 B  = 1536 16B chunks
#pragma unroll
      for (int rnd = 0; rnd < 6; ++rnd) {
        int c  = rnd * 256 + t;
        int kw = c >> 9;
        int m  = (c >> 2) & 127;
        int j  = c & 3;
        const __hip_bfloat16* g =
            wt + (((size_t)((kh * 3 + kw) * 256 + co0 + m)) << 8) + ci0 + (j << 3);
        async_copy16(g, &As[c << 3]);
      }
      // stage B: 130 haloed w-rows x 64 B = 520 chunks
#pragma unroll
      for (int rnd = 0; rnd < 2; ++rnd) {
        int c = rnd * 256 + t;
        int r = c >> 2;
        int j = c & 3;
        int wp = w0 - 1 + r;
        const __hip_bfloat16* g = (hok && (unsigned)wp < (unsigned)WWD)
            ? xrow + ((size_t)wp << 8) + ci0 + (j << 3)
            : zb + (j << 3);
        async_copy16(g, &Bs[c << 3]);
      }
      if (t < 8) {
        int c = 512 + t;
        int r = c >> 2;
        int j = c & 3;
        int wp = w0 - 1 + r;
        const __hip_bfloat16* g = (hok && (unsigned)wp < (unsigned)WWD)
            ? xrow + ((size_t)wp << 8) + ci0 + (j << 3)
            : zb + (j << 3);
        async_copy16(g, &Bs[c << 3]);
      }
      __syncthreads();

#pragma unroll
      for (int kw = 0; kw < 3; ++kw) {
        bf16x8 af[4], bfr[4];
#pragma unroll
        for (int mi = 0; mi < 4; ++mi)
          af[mi] = *(const bf16x8*)&As[(kw << 12) + ((wm * 64 + mi * 16 + mcol) << 5) + (krow << 3)];
#pragma unroll
        for (int ni = 0; ni < 4; ++ni)
          bfr[ni] = *(const bf16x8*)&Bs[((wn * 64 + ni * 16 + mcol + kw) << 5) + (krow << 3)];
#pragma unroll
        for (int mi = 0; mi < 4; ++mi)
#pragma unroll
          for (int ni = 0; ni < 4; ++ni)
            acc[mi][ni] = __builtin_amdgcn_mfma_f32_16x16x32_bf16(
                af[mi], bfr[ni], acc[mi][ni], 0, 0, 0);
      }
    }
  }

  // epilogue: D col = lane&15, row = (lane>>4)*4 + reg (m91-verified)
  const size_t outrow = (size_t)h * WWD;
#pragma unroll
  for (int mi = 0; mi < 4; ++mi) {
#pragma unroll
    for (int r = 0; r < 4; ++r) {
      int co = co0 + wm * 64 + mi * 16 + krow * 4 + r;
      float bv = bias[co];
      float* op = out + (size_t)co * HWSZ + outrow + w0 + wn * 64 + mcol;
#pragma unroll
      for (int ni = 0; ni < 4; ++ni)
        op[ni * 16] = acc[mi][ni][r] + bv;
    }
  }
}

// ---------------- fallback: naive fp32 direct conv (only if ws too small) ----------------
__global__ __launch_bounds__(256) void conv_naive(
    const float* __restrict__ x, const float* __restrict__ Wf,
    const float* __restrict__ bias, float* __restrict__ out)
{
  size_t idx = (size_t)blockIdx.x * 256 + threadIdx.x;
  int w  = (int)(idx & 511);
  int h  = (int)((idx >> 9) & 511);
  int co = (int)(idx >> 18);
  float acc = bias[co];
  for (int kh = 0; kh < 3; ++kh) {
    int hp = h + kh - 1;
    if ((unsigned)hp >= 512u) continue;
    for (int kw = 0; kw < 3; ++kw) {
      int wp = w + kw - 1;
      if ((unsigned)wp >= 512u) continue;
      const float* wcol = Wf + ((size_t)(kh * 3 + kw) << 16) + co;
      const float* xpix = x + (size_t)hp * 512 + wp;
      for (int ci = 0; ci < 256; ++ci)
        acc += xpix[(size_t)ci * HWSZ] * wcol[(size_t)ci << 8];
    }
  }
  out[idx] = acc;
}

extern "C" void kernel_launch(void* const* d_in, const int* in_sizes, int n_in,
                              void* d_out, int out_size, void* d_ws, size_t ws_size,
                              hipStream_t stream) {
  const float* x    = (const float*)d_in[0];
  const float* Wf   = (const float*)d_in[1];
  const float* bias = (const float*)d_in[2];
  float* out = (float*)d_out;

  const size_t xt_bytes = (size_t)HH * WWD * CIN * 2;        // 134217728
  const size_t wt_bytes = (size_t)9 * 256 * 256 * 2;         // 1179648
  const size_t need = xt_bytes + wt_bytes + 256;

  if (ws_size >= need) {
    __hip_bfloat16* xt = (__hip_bfloat16*)d_ws;
    __hip_bfloat16* wt = (__hip_bfloat16*)((char*)d_ws + xt_bytes);
    __hip_bfloat16* zb = (__hip_bfloat16*)((char*)d_ws + xt_bytes + wt_bytes);
    convert_x<<<4096, 256, 0, stream>>>(x, xt);
    convert_w<<<2304, 256, 0, stream>>>(Wf, wt, zb);
    conv_mfma<<<4096, 256, 0, stream>>>(xt, wt, bias, out, zb);
  } else {
    conv_naive<<<262144, 256, 0, stream>>>(x, Wf, bias, out);
  }
}